// Round 3
// baseline (220.014 us; speedup 1.0000x reference)
//
#include <hip/hip_runtime.h>
#include <math.h>

#define N 4096
#define DQ 128
#define DIN 64
#define DC 32
#define NT 9          // full B panel: 9 n-tiles (128 v cols + z tile)
#define PST9 144
#define NIT 256       // N/16 i-tiles
#define KB 4          // grid k-splits (rounds 1-2)
#define SW 8          // k-steps per wave: N / KB / 32 rows / 4 waves
#define ELS 260       // kExp LDS row stride

typedef __attribute__((ext_vector_type(8))) short short8;
typedef __attribute__((ext_vector_type(8))) _Float16 half8;
typedef __attribute__((ext_vector_type(4))) float f32x4;

__device__ __forceinline__ unsigned short f2h(float x) {
  return __builtin_bit_cast(unsigned short, (_Float16)x);
}
__device__ __forceinline__ half8 ldfrag(const unsigned short* p) {
  return __builtin_bit_cast(half8, *(const short8*)p);
}

// ---- shared epilogue: p*(h@W_av+b_av) -> single f16 into LDS tile -----------
__device__ __forceinline__ void v_phase(const float* hs_row, float p,
    const float* __restrict__ W_av_k, const float* __restrict__ b_av_k,
    int r, int d4, unsigned short* shh) {
  float a[4] = {b_av_k[d4], b_av_k[d4 + 1], b_av_k[d4 + 2], b_av_k[d4 + 3]};
  for (int c = 0; c < DQ; ++c) {
    const float hv = hs_row[c];
    const float4 w = *(const float4*)&W_av_k[c * DQ + d4];
    a[0] += hv * w.x; a[1] += hv * w.y; a[2] += hv * w.z; a[3] += hv * w.w;
  }
  const int nt = d4 >> 4;
#pragma unroll
  for (int e = 0; e < 4; ++e)
    shh[nt * 128 + ((d4 + e) & 15) * 8 + r] = f2h(p * a[e]);
  const int c32 = d4 >> 2;
  if (c32 < 16)
    shh[8 * 128 + c32 * 8 + r] = (c32 == 0) ? f2h(p) : 0;
}

__device__ __forceinline__ void v_store(int tid, int blk,
    const unsigned short* shh, unsigned short* __restrict__ Vf) {
  const int kt = blk >> 2, quad = blk & 3;
  if (tid < NT * 16) {
    const int nt = tid >> 4, l15 = tid & 15;
    const size_t dst = (((size_t)kt * NT + nt) * 64 + quad * 16 + l15) * 8;
    *(short8*)(Vf + dst) = *(const short8*)&shh[nt * 128 + l15 * 8];
  }
}

// ---- fused kExp + kVS0: independent work, one dispatch ----------------------
// blocks [0,2048): Ef = f16(exp(trans)) in MFMA A-frag layout (32x256 panel).
// blocks [2048,2560): encode + sa + p + V' (8 rows per block).
__global__ __launch_bounds__(256) void kPre(
    const float* __restrict__ trans, unsigned short* __restrict__ Ef,
    const float* __restrict__ x, const float* __restrict__ comms,
    const float* __restrict__ W_enc, const float* __restrict__ b_enc,
    const float* __restrict__ W_ad_k, const float* __restrict__ wa,
    const float* __restrict__ W_av_k, const float* __restrict__ b_av_k,
    unsigned short* __restrict__ Vf) {
  __shared__ __align__(16) char smem[32 * ELS * 4];
  const int tid = threadIdx.x;
  if (blockIdx.x < 2048) {
    // ---------------- kExp path ----------------
    float* sh = (float*)smem;
    const int ip = blockIdx.x & 15;   // i-panel of 256 (0..15)
    const int kt = blockIdx.x >> 4;   // k-tile of 32 (0..127)
    float4 v[8];
#pragma unroll
    for (int p = 0; p < 8; ++p) {
      const int f = p * 256 + tid;
      const int r = f >> 6, c = (f & 63) << 2;
      v[p] = *(const float4*)&trans[((size_t)kt * 32 + r) * N + ip * 256 + c];
    }
#pragma unroll
    for (int p = 0; p < 8; ++p) {
      const int f = p * 256 + tid;
      const int r = f >> 6, c = (f & 63) << 2;
      float4 e;
      e.x = __expf(v[p].x); e.y = __expf(v[p].y);
      e.z = __expf(v[p].z); e.w = __expf(v[p].w);
      *(float4*)&sh[r * ELS + c] = e;
    }
    __syncthreads();
    const int w = tid >> 6, lane = tid & 63;
    const int quad = lane >> 4, l15 = lane & 15;
#pragma unroll
    for (int s = 0; s < 4; ++s) {
      const int col = 64 * w + s * 16 + l15;
      unsigned short hb[8];
#pragma unroll
      for (int jj = 0; jj < 8; ++jj)
        hb[jj] = f2h(sh[(quad * 8 + jj) * ELS + col]);
      const short8 sv = {(short)hb[0], (short)hb[1], (short)hb[2], (short)hb[3],
                         (short)hb[4], (short)hb[5], (short)hb[6], (short)hb[7]};
      const int itt = ip * 16 + 4 * w + s;
      *(short8*)(Ef + (((size_t)kt * NIT + itt) * 64 + lane) * 8) = sv;
    }
  } else {
    // ---------------- kVS0 path ----------------
    const int blk = blockIdx.x - 2048;
    float(*xs)[96] = (float(*)[96])smem;                       // 3072 B
    float(*hs)[DQ] = (float(*)[DQ])(smem + 3072);              // 4096 B
    float* u = (float*)(smem + 7168);                          // 512 B
    float* pb = (float*)(smem + 7680);                         // 32 B
    unsigned short* shh = (unsigned short*)(smem + 7712);      // 2304 B
    if (tid < 128) {
      const float4 vv = *(const float4*)&x[(size_t)blk * 8 * DIN + tid * 4];
      const int idx = tid * 4, r = idx >> 6, c = idx & 63;
      xs[r][c] = vv.x; xs[r][c + 1] = vv.y; xs[r][c + 2] = vv.z; xs[r][c + 3] = vv.w;
    } else if (tid < 192) {
      const int t = tid - 128;
      const float4 vv = *(const float4*)&comms[(size_t)blk * 8 * DC + t * 4];
      const int idx = t * 4, r = idx >> 5, c = idx & 31;
      xs[r][64 + c] = vv.x; xs[r][64 + c + 1] = vv.y;
      xs[r][64 + c + 2] = vv.z; xs[r][64 + c + 3] = vv.w;
    }
    if (tid < DQ) {
      float s = 0.f;
      const float* wrow = &W_ad_k[tid * DQ];
      for (int q = 0; q < DQ; ++q) s += wrow[q] * wa[q];
      u[tid] = s;
    }
    __syncthreads();
    const int r = tid >> 5;
    const int c32 = tid & 31;
    const int d4 = c32 * 4;
    {
      float a0 = b_enc[d4], a1 = b_enc[d4 + 1], a2 = b_enc[d4 + 2], a3 = b_enc[d4 + 3];
      for (int c = 0; c < 96; ++c) {
        const float hv = xs[r][c];
        const float4 w = *(const float4*)&W_enc[c * DQ + d4];
        a0 += hv * w.x; a1 += hv * w.y; a2 += hv * w.z; a3 += hv * w.w;
      }
      hs[r][d4] = a0; hs[r][d4 + 1] = a1; hs[r][d4 + 2] = a2; hs[r][d4 + 3] = a3;
    }
    __syncthreads();
    float part = 0.f;
    for (int c = c32; c < DQ; c += 32) part += hs[r][c] * u[c];
#pragma unroll
    for (int m = 16; m > 0; m >>= 1) part += __shfl_xor(part, m, 32);
    if (c32 == 0) pb[r] = __expf(part);
    __syncthreads();
    v_phase(hs[r], pb[r], W_av_k, b_av_k, r, d4, shh);
    __syncthreads();
    v_store(tid, blk, shh, Vf);
  }
}

// ---- round 1: P-reduce -> h + sa + p + V' (full panel) ----
__global__ __launch_bounds__(256) void kVSR(const float* __restrict__ P,
    const float* __restrict__ W_ad_k, const float* __restrict__ wa,
    const float* __restrict__ W_av_k, const float* __restrict__ b_av_k,
    unsigned short* __restrict__ Vf) {
  __shared__ float hs[8][DQ];
  __shared__ float u[DQ];
  __shared__ float pb[8];
  __shared__ __align__(16) unsigned short shh[NT * 128];
  const int tid = threadIdx.x;
  const int r = tid >> 5;
  const int c32 = tid & 31;
  const int d4 = c32 * 4;
  const int j = blockIdx.x * 8 + r;
  if (tid < DQ) {
    float s = 0.f;
    const float* wrow = &W_ad_k[tid * DQ];
    for (int q = 0; q < DQ; ++q) s += wrow[q] * wa[q];
    u[tid] = s;
  }
  float4 num = {0.f, 0.f, 0.f, 0.f};
  float den = 0.f;
#pragma unroll
  for (int s = 0; s < KB; ++s) {
    const float* b = &P[((size_t)s * N + j) * PST9];
    const float4 v = *(const float4*)&b[d4];
    num.x += v.x; num.y += v.y; num.z += v.z; num.w += v.w;
    den += b[128];
  }
  const float inv = 1.f / den;
  hs[r][d4] = num.x * inv; hs[r][d4 + 1] = num.y * inv;
  hs[r][d4 + 2] = num.z * inv; hs[r][d4 + 3] = num.w * inv;
  __syncthreads();
  float part = 0.f;
  for (int c = c32; c < DQ; c += 32) part += hs[r][c] * u[c];
#pragma unroll
  for (int m = 16; m > 0; m >>= 1) part += __shfl_xor(part, m, 32);
  if (c32 == 0) pb[r] = __expf(part);
  __syncthreads();
  v_phase(hs[r], pb[r], W_av_k, b_av_k, r, d4, shh);
  __syncthreads();
  v_store(tid, blockIdx.x, shh, Vf);
}

// ---- round 2: P-reduce -> h + sa + p + CONTRACTED V' (v.W_dec, p) ----
__global__ __launch_bounds__(256) void kVSRc(const float* __restrict__ P,
    const float* __restrict__ W_ad_k, const float* __restrict__ wa,
    const float* __restrict__ W_av_k, const float* __restrict__ b_av_k,
    const float* __restrict__ W_dec, unsigned short* __restrict__ Vc) {
  __shared__ float hs[8][DQ];
  __shared__ float u[DQ];
  __shared__ float pb[8];
  const int tid = threadIdx.x;
  const int r = tid >> 5;
  const int c32 = tid & 31;
  const int d4 = c32 * 4;
  const int j = blockIdx.x * 8 + r;
  if (tid < DQ) {
    float s = 0.f;
    const float* wrow = &W_ad_k[tid * DQ];
    for (int q = 0; q < DQ; ++q) s += wrow[q] * wa[q];
    u[tid] = s;
  }
  float4 num = {0.f, 0.f, 0.f, 0.f};
  float den = 0.f;
#pragma unroll
  for (int s = 0; s < KB; ++s) {
    const float* b = &P[((size_t)s * N + j) * PST9];
    const float4 v = *(const float4*)&b[d4];
    num.x += v.x; num.y += v.y; num.z += v.z; num.w += v.w;
    den += b[128];
  }
  const float inv = 1.f / den;
  hs[r][d4] = num.x * inv; hs[r][d4 + 1] = num.y * inv;
  hs[r][d4 + 2] = num.z * inv; hs[r][d4 + 3] = num.w * inv;
  __syncthreads();
  float part = 0.f;
  for (int c = c32; c < DQ; c += 32) part += hs[r][c] * u[c];
#pragma unroll
  for (int m = 16; m > 0; m >>= 1) part += __shfl_xor(part, m, 32);
  if (c32 == 0) pb[r] = __expf(part);
  __syncthreads();
  float a[4] = {b_av_k[d4], b_av_k[d4 + 1], b_av_k[d4 + 2], b_av_k[d4 + 3]};
  for (int c = 0; c < DQ; ++c) {
    const float hv = hs[r][c];
    const float4 w = *(const float4*)&W_av_k[c * DQ + d4];
    a[0] += hv * w.x; a[1] += hv * w.y; a[2] += hv * w.z; a[3] += hv * w.w;
  }
  float vd = a[0] * W_dec[d4] + a[1] * W_dec[d4 + 1]
           + a[2] * W_dec[d4 + 2] + a[3] * W_dec[d4 + 3];
#pragma unroll
  for (int m = 16; m > 0; m >>= 1) vd += __shfl_xor(vd, m, 32);
  const float p = pb[r];
  if (c32 < 16) {
    const int blk = blockIdx.x;
    const size_t ix = (((size_t)(blk >> 2)) * 64 + (blk & 3) * 16 + c32) * 8 + r;
    Vc[ix] = (c32 == 0) ? f2h(p * vd) : (c32 == 1) ? f2h(p) : 0;
  }
}

// ---- MFMA GEMM, in-block k-split; B loaded DIRECT to VGPRs (no LDS staging) -
// The old LDS staging was a byte-identity pass-through (async16 dst layout ==
// B-frag read layout), so global->reg double-buffer gives the same bytes with
// 9 fewer ds_read_b128 + 9 fewer global_load_lds issues per k-step and
// compiler-precise vmcnt. LDS retained only for the cross-wave epilogue.
template <int NTT, int PST>
__global__ __launch_bounds__(256, 2) void kGemmR(
    const unsigned short* __restrict__ Ef, const unsigned short* __restrict__ Vf,
    float* __restrict__ P) {
  __shared__ __align__(16) float lf[4 * 2 * NTT * 256];
  const int tid = threadIdx.x;
  const int w = tid >> 6, lane = tid & 63;
  const int quad = lane >> 4, l15 = lane & 15;
  const int it0 = blockIdx.x * 2;
  const size_t ktw = (size_t)blockIdx.y * (4 * SW) + w * SW;

  f32x4 acc[2][NTT];
#pragma unroll
  for (int ti = 0; ti < 2; ++ti)
#pragma unroll
    for (int nt = 0; nt < NTT; ++nt) acc[ti][nt] = (f32x4){0.f, 0.f, 0.f, 0.f};

  const unsigned short* Ap = Ef + (ktw * NIT + it0) * 512 + lane * 8;
  const unsigned short* Bp = Vf + ktw * (NTT * 512) + lane * 8;

  half8 A0[2], A1[2], B0[NTT], B1[NTT];
#pragma unroll
  for (int ti = 0; ti < 2; ++ti) A0[ti] = ldfrag(Ap + ti * 512);
#pragma unroll
  for (int nt = 0; nt < NTT; ++nt) B0[nt] = ldfrag(Bp + nt * 512);

#pragma unroll
  for (int t = 0; t < SW; ++t) {
    if (t + 1 < SW) {
      const unsigned short* An = Ap + (size_t)(t + 1) * (NIT * 512);
      const unsigned short* Bn = Bp + (size_t)(t + 1) * (NTT * 512);
#pragma unroll
      for (int nt = 0; nt < NTT; ++nt) B1[nt] = ldfrag(Bn + nt * 512);
#pragma unroll
      for (int ti = 0; ti < 2; ++ti) A1[ti] = ldfrag(An + ti * 512);
    }
#pragma unroll
    for (int nt = 0; nt < NTT; ++nt) {
      acc[0][nt] = __builtin_amdgcn_mfma_f32_16x16x32_f16(A0[0], B0[nt], acc[0][nt], 0, 0, 0);
      acc[1][nt] = __builtin_amdgcn_mfma_f32_16x16x32_f16(A0[1], B0[nt], acc[1][nt], 0, 0, 0);
    }
    if (t + 1 < SW) {
      A0[0] = A1[0]; A0[1] = A1[1];
#pragma unroll
      for (int nt = 0; nt < NTT; ++nt) B0[nt] = B1[nt];
    }
  }

#pragma unroll
  for (int ti = 0; ti < 2; ++ti)
#pragma unroll
    for (int nt = 0; nt < NTT; ++nt) {
      float4 v; v.x = acc[ti][nt][0]; v.y = acc[ti][nt][1];
      v.z = acc[ti][nt][2]; v.w = acc[ti][nt][3];
      *(float4*)&lf[(w * 2 * NTT + ti * NTT + nt) * 256 + lane * 4] = v;
    }
  __syncthreads();
  float* Pb = P + (size_t)blockIdx.y * N * PST;
  for (int p = w; p < 2 * NTT; p += 4) {
    const int ti = p / NTT, nt = p % NTT;
    float4 s = {0.f, 0.f, 0.f, 0.f};
#pragma unroll
    for (int wv = 0; wv < 4; ++wv) {
      const float4 v = *(const float4*)&lf[(wv * 2 * NTT + p) * 256 + lane * 4];
      s.x += v.x; s.y += v.y; s.z += v.z; s.w += v.w;
    }
    const float sr[4] = {s.x, s.y, s.z, s.w};
    if (NTT == 1 || nt != 8 || l15 == 0) {
#pragma unroll
      for (int r = 0; r < 4; ++r) {
        const int i = (it0 + ti) * 16 + quad * 4 + r;
        Pb[(size_t)i * PST + nt * 16 + l15] = sr[r];
      }
    }
  }
}

// ---- round 3 GEMM + out fused: 1 i-tile/block, 8 waves split full k --------
// Vc has 2 live cols (num=p*vd, den=p); reduce 8 waves in LDS, emit out[i].
// Kills the P3 buffer, the KB-split reduce, and the kOut launch.
__global__ __launch_bounds__(512, 2) void kGemmO(
    const unsigned short* __restrict__ Ef, const unsigned short* __restrict__ Vc,
    const float* __restrict__ b_dec, const int* __restrict__ mask,
    float* __restrict__ out) {
  __shared__ float red[8 * 256];
  __shared__ float nums[16], dens[16];
  const int tid = threadIdx.x;
  const int w = tid >> 6, lane = tid & 63;
  const int it = blockIdx.x;
  const int kt0 = w * 16;
  half8 Af[16], Bf[16];
#pragma unroll
  for (int t = 0; t < 16; ++t) {
    const size_t kt = kt0 + t;
    Af[t] = ldfrag(Ef + (kt * NIT + it) * 512 + lane * 8);
    Bf[t] = ldfrag(Vc + kt * 512 + lane * 8);
  }
  f32x4 acc = (f32x4){0.f, 0.f, 0.f, 0.f};
#pragma unroll
  for (int t = 0; t < 16; ++t)
    acc = __builtin_amdgcn_mfma_f32_16x16x32_f16(Af[t], Bf[t], acc, 0, 0, 0);
  float4 v; v.x = acc[0]; v.y = acc[1]; v.z = acc[2]; v.w = acc[3];
  *(float4*)&red[w * 256 + lane * 4] = v;
  __syncthreads();
  if (tid < 256) {
    const int l = tid & 63, e = tid >> 6;
    float s = 0.f;
#pragma unroll
    for (int ww = 0; ww < 8; ++ww) s += red[ww * 256 + l * 4 + e];
    const int col = l & 15, row = (l >> 4) * 4 + e;  // C-frag mapping
    if (col == 0) nums[row] = s;
    else if (col == 1) dens[row] = s;
  }
  __syncthreads();
  if (tid < 16) {
    const int i = it * 16 + tid;
    out[i] = (mask[i] == 0) ? -INFINITY : nums[tid] / dens[tid] + b_dec[0];
  }
}

extern "C" void kernel_launch(void* const* d_in, const int* in_sizes, int n_in,
                              void* d_out, int out_size, void* d_ws, size_t ws_size,
                              hipStream_t stream) {
  (void)in_sizes; (void)n_in; (void)out_size; (void)ws_size;
  const float* x     = (const float*)d_in[0];
  const float* comms = (const float*)d_in[1];
  const float* trans = (const float*)d_in[2];
  const int*   mask  = (const int*)d_in[3];
  const float* W_enc = (const float*)d_in[4];
  const float* b_enc = (const float*)d_in[5];
  const float* W_ad  = (const float*)d_in[6];
  // d_in[7]=b_ad, d_in[9]=b_att cancel inside the row softmax
  const float* w_att = (const float*)d_in[8];
  const float* W_av  = (const float*)d_in[10];
  const float* b_av  = (const float*)d_in[11];
  const float* W_dec = (const float*)d_in[12];
  const float* b_dec = (const float*)d_in[13];
  float* out         = (float*)d_out;

  char* ws = (char*)d_ws;
  unsigned short* Vf = (unsigned short*)ws;  ws += (size_t)(N / 32) * NT * 512 * 2;
  unsigned short* Vc = (unsigned short*)ws;  ws += (size_t)(N / 32) * 512 * 2;
  unsigned short* Ef = (unsigned short*)ws;  ws += (size_t)N * N * 2;
  float* P  = (float*)ws;

  kPre<<<2560, 256, 0, stream>>>(trans, Ef, x, comms, W_enc, b_enc, W_ad,
                                 w_att, W_av, b_av, Vf);
  kGemmR<NT, PST9><<<dim3(NIT / 2, KB), 256, 0, stream>>>(Ef, Vf, P);

  kVSR<<<N / 8, 256, 0, stream>>>(P, W_ad + (size_t)1 * DQ * DQ,
                                  w_att + 2 * DQ, W_av + (size_t)1 * DQ * DQ,
                                  b_av + DQ, Vf);
  kGemmR<NT, PST9><<<dim3(NIT / 2, KB), 256, 0, stream>>>(Ef, Vf, P);

  kVSRc<<<N / 8, 256, 0, stream>>>(P, W_ad + (size_t)2 * DQ * DQ,
                                   w_att + 4 * DQ, W_av + (size_t)2 * DQ * DQ,
                                   b_av + 2 * DQ, W_dec, Vc);
  kGemmO<<<NIT, 512, 0, stream>>>(Ef, Vc, b_dec, mask, out);
}

// Round 4
// 211.142 us; speedup vs baseline: 1.0420x; 1.0420x over previous
//
#include <hip/hip_runtime.h>
#include <math.h>

#define N 4096
#define DQ 128
#define DIN 64
#define DC 32
#define NT 9          // full B panel: 9 n-tiles (128 v cols + z tile)
#define PST9 144
#define NIT 256       // N/16 i-tiles
#define KB 4          // grid k-splits (rounds 1-2)
#define SW 8          // k-steps per wave: N / KB / 32 rows / 4 waves
#define TS 68         // kExp wave-tile row stride in f16 units (136B: 8B-aligned writes, quads 16 words apart on reads)

typedef __attribute__((ext_vector_type(8))) short short8;
typedef __attribute__((ext_vector_type(8))) _Float16 half8;
typedef __attribute__((ext_vector_type(4))) float f32x4;
typedef __attribute__((ext_vector_type(4))) unsigned short us4;

__device__ __forceinline__ unsigned short f2h(float x) {
  return __builtin_bit_cast(unsigned short, (_Float16)x);
}
__device__ __forceinline__ half8 ldfrag(const unsigned short* p) {
  return __builtin_bit_cast(half8, *(const short8*)p);
}

// coalesced-ish u = W_ad_k . wa (float4 row reads: 4x fewer transactions)
__device__ __forceinline__ void u_calc(int tid, const float* __restrict__ W_ad_k,
                                       const float* __restrict__ wa, float* u) {
  if (tid < DQ) {
    float s = 0.f;
    const float* wrow = &W_ad_k[tid * DQ];
    for (int q = 0; q < DQ; q += 4) {
      const float4 wv = *(const float4*)&wrow[q];
      const float4 av = *(const float4*)&wa[q];
      s += wv.x * av.x + wv.y * av.y + wv.z * av.z + wv.w * av.w;
    }
    u[tid] = s;
  }
}

// ---- shared epilogue: p*(h@W_av+b_av) -> single f16 into LDS tile -----------
__device__ __forceinline__ void v_phase(const float* hs_row, float p,
    const float* __restrict__ W_av_k, const float* __restrict__ b_av_k,
    int r, int d4, unsigned short* shh) {
  float a[4] = {b_av_k[d4], b_av_k[d4 + 1], b_av_k[d4 + 2], b_av_k[d4 + 3]};
  for (int c = 0; c < DQ; ++c) {
    const float hv = hs_row[c];
    const float4 w = *(const float4*)&W_av_k[c * DQ + d4];
    a[0] += hv * w.x; a[1] += hv * w.y; a[2] += hv * w.z; a[3] += hv * w.w;
  }
  const int nt = d4 >> 4;
#pragma unroll
  for (int e = 0; e < 4; ++e)
    shh[nt * 128 + ((d4 + e) & 15) * 8 + r] = f2h(p * a[e]);
  const int c32 = d4 >> 2;
  if (c32 < 16)
    shh[8 * 128 + c32 * 8 + r] = (c32 == 0) ? f2h(p) : 0;
}

__device__ __forceinline__ void v_store(int tid, int blk,
    const unsigned short* shh, unsigned short* __restrict__ Vf) {
  const int kt = blk >> 2, quad = blk & 3;
  if (tid < NT * 16) {
    const int nt = tid >> 4, l15 = tid & 15;
    const size_t dst = (((size_t)kt * NT + nt) * 64 + quad * 16 + l15) * 8;
    *(short8*)(Vf + dst) = *(const short8*)&shh[nt * 128 + l15 * 8];
  }
}

// ---- fused kVS0 + kExp: VS0 blocks FIRST (overlap, no tail) -----------------
// blocks [0,512): encode + sa + p + V' (8 rows per block).
// blocks [512,2560): Ef = f16(exp(trans)) in MFMA A-frag layout.
//   kExp path is BARRIER-FREE: each wave owns a private 32x64 column slice
//   (f16 LDS tile, stride TS), loads -> exp -> cvt -> LDS -> in-wave transpose.
//   17.4 KB LDS => ~9 blocks/CU; whole exp grid co-resident => deep HBM queue.
__global__ __launch_bounds__(256) void kPre(
    const float* __restrict__ trans, unsigned short* __restrict__ Ef,
    const float* __restrict__ x, const float* __restrict__ comms,
    const float* __restrict__ W_enc, const float* __restrict__ b_enc,
    const float* __restrict__ W_ad_k, const float* __restrict__ wa,
    const float* __restrict__ W_av_k, const float* __restrict__ b_av_k,
    unsigned short* __restrict__ Vf) {
  __shared__ __align__(16) char smem[4 * 32 * TS * 2];  // 17408 B
  const int tid = threadIdx.x;
  if (blockIdx.x >= 512) {
    // ---------------- kExp path (wave-private, no __syncthreads) ----------
    const int bid = blockIdx.x - 512;
    const int ip = bid & 15;          // i-panel of 256 (0..15)
    const int kt = bid >> 4;          // k-tile of 32 (0..127)
    const int w = tid >> 6, lane = tid & 63;
    const int quad = lane >> 4, l15 = lane & 15;
    unsigned short* lt = (unsigned short*)smem + w * (32 * TS);
    float4 v[8];
#pragma unroll
    for (int p = 0; p < 8; ++p) {
      const int r = 4 * p + quad;
      v[p] = *(const float4*)&trans[((size_t)(kt * 32 + r)) * N + ip * 256 + w * 64 + 4 * l15];
    }
#pragma unroll
    for (int p = 0; p < 8; ++p) {
      const int r = 4 * p + quad;
      us4 pv;
      pv.x = f2h(__expf(v[p].x)); pv.y = f2h(__expf(v[p].y));
      pv.z = f2h(__expf(v[p].z)); pv.w = f2h(__expf(v[p].w));
      *(us4*)&lt[r * TS + 4 * l15] = pv;
    }
    // in-wave fence: writes above feed reads below (cross-lane, same wave)
    asm volatile("s_waitcnt lgkmcnt(0)" ::: "memory");
#pragma unroll
    for (int s = 0; s < 4; ++s) {
      unsigned short hb[8];
#pragma unroll
      for (int jj = 0; jj < 8; ++jj)
        hb[jj] = lt[(quad * 8 + jj) * TS + s * 16 + l15];
      const short8 sv = {(short)hb[0], (short)hb[1], (short)hb[2], (short)hb[3],
                         (short)hb[4], (short)hb[5], (short)hb[6], (short)hb[7]};
      const int itt = ip * 16 + 4 * w + s;
      *(short8*)(Ef + (((size_t)kt * NIT + itt) * 64 + lane) * 8) = sv;
    }
  } else {
    // ---------------- kVS0 path ----------------
    const int blk = blockIdx.x;
    float(*xs)[96] = (float(*)[96])smem;                       // 3072 B
    float(*hs)[DQ] = (float(*)[DQ])(smem + 3072);              // 4096 B
    float* u = (float*)(smem + 7168);                          // 512 B
    float* pb = (float*)(smem + 7680);                         // 32 B
    unsigned short* shh = (unsigned short*)(smem + 7712);      // 2304 B
    if (tid < 128) {
      const float4 vv = *(const float4*)&x[(size_t)blk * 8 * DIN + tid * 4];
      const int idx = tid * 4, r = idx >> 6, c = idx & 63;
      xs[r][c] = vv.x; xs[r][c + 1] = vv.y; xs[r][c + 2] = vv.z; xs[r][c + 3] = vv.w;
    } else if (tid < 192) {
      const int t = tid - 128;
      const float4 vv = *(const float4*)&comms[(size_t)blk * 8 * DC + t * 4];
      const int idx = t * 4, r = idx >> 5, c = idx & 31;
      xs[r][64 + c] = vv.x; xs[r][64 + c + 1] = vv.y;
      xs[r][64 + c + 2] = vv.z; xs[r][64 + c + 3] = vv.w;
    }
    u_calc(tid, W_ad_k, wa, u);
    __syncthreads();
    const int r = tid >> 5;
    const int c32 = tid & 31;
    const int d4 = c32 * 4;
    {
      float a0 = b_enc[d4], a1 = b_enc[d4 + 1], a2 = b_enc[d4 + 2], a3 = b_enc[d4 + 3];
      for (int c = 0; c < 96; ++c) {
        const float hv = xs[r][c];
        const float4 w = *(const float4*)&W_enc[c * DQ + d4];
        a0 += hv * w.x; a1 += hv * w.y; a2 += hv * w.z; a3 += hv * w.w;
      }
      hs[r][d4] = a0; hs[r][d4 + 1] = a1; hs[r][d4 + 2] = a2; hs[r][d4 + 3] = a3;
    }
    __syncthreads();
    float part = 0.f;
    for (int c = c32; c < DQ; c += 32) part += hs[r][c] * u[c];
#pragma unroll
    for (int m = 16; m > 0; m >>= 1) part += __shfl_xor(part, m, 32);
    if (c32 == 0) pb[r] = __expf(part);
    __syncthreads();
    v_phase(hs[r], pb[r], W_av_k, b_av_k, r, d4, shh);
    __syncthreads();
    v_store(tid, blk, shh, Vf);
  }
}

// ---- round 1: P-reduce -> h + sa + p + V' (full panel) ----
__global__ __launch_bounds__(256) void kVSR(const float* __restrict__ P,
    const float* __restrict__ W_ad_k, const float* __restrict__ wa,
    const float* __restrict__ W_av_k, const float* __restrict__ b_av_k,
    unsigned short* __restrict__ Vf) {
  __shared__ float hs[8][DQ];
  __shared__ float u[DQ];
  __shared__ float pb[8];
  __shared__ __align__(16) unsigned short shh[NT * 128];
  const int tid = threadIdx.x;
  const int r = tid >> 5;
  const int c32 = tid & 31;
  const int d4 = c32 * 4;
  const int j = blockIdx.x * 8 + r;
  u_calc(tid, W_ad_k, wa, u);
  float4 num = {0.f, 0.f, 0.f, 0.f};
  float den = 0.f;
#pragma unroll
  for (int s = 0; s < KB; ++s) {
    const float* b = &P[((size_t)s * N + j) * PST9];
    const float4 v = *(const float4*)&b[d4];
    num.x += v.x; num.y += v.y; num.z += v.z; num.w += v.w;
    den += b[128];
  }
  const float inv = 1.f / den;
  hs[r][d4] = num.x * inv; hs[r][d4 + 1] = num.y * inv;
  hs[r][d4 + 2] = num.z * inv; hs[r][d4 + 3] = num.w * inv;
  __syncthreads();
  float part = 0.f;
  for (int c = c32; c < DQ; c += 32) part += hs[r][c] * u[c];
#pragma unroll
  for (int m = 16; m > 0; m >>= 1) part += __shfl_xor(part, m, 32);
  if (c32 == 0) pb[r] = __expf(part);
  __syncthreads();
  v_phase(hs[r], pb[r], W_av_k, b_av_k, r, d4, shh);
  __syncthreads();
  v_store(tid, blockIdx.x, shh, Vf);
}

// ---- round 2: P-reduce -> h + sa + p + CONTRACTED V' (v.W_dec, p) ----
__global__ __launch_bounds__(256) void kVSRc(const float* __restrict__ P,
    const float* __restrict__ W_ad_k, const float* __restrict__ wa,
    const float* __restrict__ W_av_k, const float* __restrict__ b_av_k,
    const float* __restrict__ W_dec, unsigned short* __restrict__ Vc) {
  __shared__ float hs[8][DQ];
  __shared__ float u[DQ];
  __shared__ float pb[8];
  const int tid = threadIdx.x;
  const int r = tid >> 5;
  const int c32 = tid & 31;
  const int d4 = c32 * 4;
  const int j = blockIdx.x * 8 + r;
  u_calc(tid, W_ad_k, wa, u);
  float4 num = {0.f, 0.f, 0.f, 0.f};
  float den = 0.f;
#pragma unroll
  for (int s = 0; s < KB; ++s) {
    const float* b = &P[((size_t)s * N + j) * PST9];
    const float4 v = *(const float4*)&b[d4];
    num.x += v.x; num.y += v.y; num.z += v.z; num.w += v.w;
    den += b[128];
  }
  const float inv = 1.f / den;
  hs[r][d4] = num.x * inv; hs[r][d4 + 1] = num.y * inv;
  hs[r][d4 + 2] = num.z * inv; hs[r][d4 + 3] = num.w * inv;
  __syncthreads();
  float part = 0.f;
  for (int c = c32; c < DQ; c += 32) part += hs[r][c] * u[c];
#pragma unroll
  for (int m = 16; m > 0; m >>= 1) part += __shfl_xor(part, m, 32);
  if (c32 == 0) pb[r] = __expf(part);
  __syncthreads();
  float a[4] = {b_av_k[d4], b_av_k[d4 + 1], b_av_k[d4 + 2], b_av_k[d4 + 3]};
  for (int c = 0; c < DQ; ++c) {
    const float hv = hs[r][c];
    const float4 w = *(const float4*)&W_av_k[c * DQ + d4];
    a[0] += hv * w.x; a[1] += hv * w.y; a[2] += hv * w.z; a[3] += hv * w.w;
  }
  float vd = a[0] * W_dec[d4] + a[1] * W_dec[d4 + 1]
           + a[2] * W_dec[d4 + 2] + a[3] * W_dec[d4 + 3];
#pragma unroll
  for (int m = 16; m > 0; m >>= 1) vd += __shfl_xor(vd, m, 32);
  const float p = pb[r];
  if (c32 < 16) {
    const int blk = blockIdx.x;
    const size_t ix = (((size_t)(blk >> 2)) * 64 + (blk & 3) * 16 + c32) * 8 + r;
    Vc[ix] = (c32 == 0) ? f2h(p * vd) : (c32 == 1) ? f2h(p) : 0;
  }
}

// ---- MFMA GEMM, in-block k-split; B loaded DIRECT to VGPRs (no LDS staging) -
template <int NTT, int PST>
__global__ __launch_bounds__(256, 2) void kGemmR(
    const unsigned short* __restrict__ Ef, const unsigned short* __restrict__ Vf,
    float* __restrict__ P) {
  __shared__ __align__(16) float lf[4 * 2 * NTT * 256];
  const int tid = threadIdx.x;
  const int w = tid >> 6, lane = tid & 63;
  const int quad = lane >> 4, l15 = lane & 15;
  const int it0 = blockIdx.x * 2;
  const size_t ktw = (size_t)blockIdx.y * (4 * SW) + w * SW;

  f32x4 acc[2][NTT];
#pragma unroll
  for (int ti = 0; ti < 2; ++ti)
#pragma unroll
    for (int nt = 0; nt < NTT; ++nt) acc[ti][nt] = (f32x4){0.f, 0.f, 0.f, 0.f};

  const unsigned short* Ap = Ef + (ktw * NIT + it0) * 512 + lane * 8;
  const unsigned short* Bp = Vf + ktw * (NTT * 512) + lane * 8;

  half8 A0[2], A1[2], B0[NTT], B1[NTT];
#pragma unroll
  for (int ti = 0; ti < 2; ++ti) A0[ti] = ldfrag(Ap + ti * 512);
#pragma unroll
  for (int nt = 0; nt < NTT; ++nt) B0[nt] = ldfrag(Bp + nt * 512);

#pragma unroll
  for (int t = 0; t < SW; ++t) {
    if (t + 1 < SW) {
      const unsigned short* An = Ap + (size_t)(t + 1) * (NIT * 512);
      const unsigned short* Bn = Bp + (size_t)(t + 1) * (NTT * 512);
#pragma unroll
      for (int nt = 0; nt < NTT; ++nt) B1[nt] = ldfrag(Bn + nt * 512);
#pragma unroll
      for (int ti = 0; ti < 2; ++ti) A1[ti] = ldfrag(An + ti * 512);
    }
#pragma unroll
    for (int nt = 0; nt < NTT; ++nt) {
      acc[0][nt] = __builtin_amdgcn_mfma_f32_16x16x32_f16(A0[0], B0[nt], acc[0][nt], 0, 0, 0);
      acc[1][nt] = __builtin_amdgcn_mfma_f32_16x16x32_f16(A0[1], B0[nt], acc[1][nt], 0, 0, 0);
    }
    if (t + 1 < SW) {
      A0[0] = A1[0]; A0[1] = A1[1];
#pragma unroll
      for (int nt = 0; nt < NTT; ++nt) B0[nt] = B1[nt];
    }
  }

#pragma unroll
  for (int ti = 0; ti < 2; ++ti)
#pragma unroll
    for (int nt = 0; nt < NTT; ++nt) {
      float4 v; v.x = acc[ti][nt][0]; v.y = acc[ti][nt][1];
      v.z = acc[ti][nt][2]; v.w = acc[ti][nt][3];
      *(float4*)&lf[(w * 2 * NTT + ti * NTT + nt) * 256 + lane * 4] = v;
    }
  __syncthreads();
  float* Pb = P + (size_t)blockIdx.y * N * PST;
  for (int p = w; p < 2 * NTT; p += 4) {
    const int ti = p / NTT, nt = p % NTT;
    float4 s = {0.f, 0.f, 0.f, 0.f};
#pragma unroll
    for (int wv = 0; wv < 4; ++wv) {
      const float4 v = *(const float4*)&lf[(wv * 2 * NTT + p) * 256 + lane * 4];
      s.x += v.x; s.y += v.y; s.z += v.z; s.w += v.w;
    }
    const float sr[4] = {s.x, s.y, s.z, s.w};
    if (NTT == 1 || nt != 8 || l15 == 0) {
#pragma unroll
      for (int r = 0; r < 4; ++r) {
        const int i = (it0 + ti) * 16 + quad * 4 + r;
        Pb[(size_t)i * PST + nt * 16 + l15] = sr[r];
      }
    }
  }
}

// ---- round 3 GEMM + out fused: 1 i-tile/block, 8 waves split full k --------
__global__ __launch_bounds__(512, 2) void kGemmO(
    const unsigned short* __restrict__ Ef, const unsigned short* __restrict__ Vc,
    const float* __restrict__ b_dec, const int* __restrict__ mask,
    float* __restrict__ out) {
  __shared__ float red[8 * 256];
  __shared__ float nums[16], dens[16];
  const int tid = threadIdx.x;
  const int w = tid >> 6, lane = tid & 63;
  const int it = blockIdx.x;
  const int kt0 = w * 16;
  half8 Af[16], Bf[16];
#pragma unroll
  for (int t = 0; t < 16; ++t) {
    const size_t kt = kt0 + t;
    Af[t] = ldfrag(Ef + (kt * NIT + it) * 512 + lane * 8);
    Bf[t] = ldfrag(Vc + kt * 512 + lane * 8);
  }
  f32x4 acc = (f32x4){0.f, 0.f, 0.f, 0.f};
#pragma unroll
  for (int t = 0; t < 16; ++t)
    acc = __builtin_amdgcn_mfma_f32_16x16x32_f16(Af[t], Bf[t], acc, 0, 0, 0);
  float4 v; v.x = acc[0]; v.y = acc[1]; v.z = acc[2]; v.w = acc[3];
  *(float4*)&red[w * 256 + lane * 4] = v;
  __syncthreads();
  if (tid < 256) {
    const int l = tid & 63, e = tid >> 6;
    float s = 0.f;
#pragma unroll
    for (int ww = 0; ww < 8; ++ww) s += red[ww * 256 + l * 4 + e];
    const int col = l & 15, row = (l >> 4) * 4 + e;  // C-frag mapping
    if (col == 0) nums[row] = s;
    else if (col == 1) dens[row] = s;
  }
  __syncthreads();
  if (tid < 16) {
    const int i = it * 16 + tid;
    out[i] = (mask[i] == 0) ? -INFINITY : nums[tid] / dens[tid] + b_dec[0];
  }
}

extern "C" void kernel_launch(void* const* d_in, const int* in_sizes, int n_in,
                              void* d_out, int out_size, void* d_ws, size_t ws_size,
                              hipStream_t stream) {
  (void)in_sizes; (void)n_in; (void)out_size; (void)ws_size;
  const float* x     = (const float*)d_in[0];
  const float* comms = (const float*)d_in[1];
  const float* trans = (const float*)d_in[2];
  const int*   mask  = (const int*)d_in[3];
  const float* W_enc = (const float*)d_in[4];
  const float* b_enc = (const float*)d_in[5];
  const float* W_ad  = (const float*)d_in[6];
  // d_in[7]=b_ad, d_in[9]=b_att cancel inside the row softmax
  const float* w_att = (const float*)d_in[8];
  const float* W_av  = (const float*)d_in[10];
  const float* b_av  = (const float*)d_in[11];
  const float* W_dec = (const float*)d_in[12];
  const float* b_dec = (const float*)d_in[13];
  float* out         = (float*)d_out;

  char* ws = (char*)d_ws;
  unsigned short* Vf = (unsigned short*)ws;  ws += (size_t)(N / 32) * NT * 512 * 2;
  unsigned short* Vc = (unsigned short*)ws;  ws += (size_t)(N / 32) * 512 * 2;
  unsigned short* Ef = (unsigned short*)ws;  ws += (size_t)N * N * 2;
  float* P  = (float*)ws;

  kPre<<<2560, 256, 0, stream>>>(trans, Ef, x, comms, W_enc, b_enc, W_ad,
                                 w_att, W_av, b_av, Vf);
  kGemmR<NT, PST9><<<dim3(NIT / 2, KB), 256, 0, stream>>>(Ef, Vf, P);

  kVSR<<<N / 8, 256, 0, stream>>>(P, W_ad + (size_t)1 * DQ * DQ,
                                  w_att + 2 * DQ, W_av + (size_t)1 * DQ * DQ,
                                  b_av + DQ, Vf);
  kGemmR<NT, PST9><<<dim3(NIT / 2, KB), 256, 0, stream>>>(Ef, Vf, P);

  kVSRc<<<N / 8, 256, 0, stream>>>(P, W_ad + (size_t)2 * DQ * DQ,
                                   w_att + 4 * DQ, W_av + (size_t)2 * DQ * DQ,
                                   b_av + 2 * DQ, W_dec, Vc);
  kGemmO<<<NIT, 512, 0, stream>>>(Ef, Vc, b_dec, mask, out);
}